// Round 1
// 5024.368 us; speedup vs baseline: 1.7259x; 1.7259x over previous
//
#include <hip/hip_runtime.h>

// LSTM_3813930958978: T=512, B=64, I=1024, H=1024, gate order i,f,g,o.
// Persistent cooperative kernel, 128 blocks x 256 threads (1 block/CU).
// Block k owns h-columns [8k, 8k+8) => 32 gate columns.
// Weights live in registers as MFMA B-fragments (K split over 2 waves per
// matrix). Waves 0,1 compute x_t @ W_ih^T (never wait on the global
// barrier); waves 2,3 poll the epoch word, then compute h @ W_hh^T.
//
// R1 (this round): coherence-flag surgery — kill the per-step L2
// writeback/invalidate fences that were bouncing h through HBM
// (FETCH_SIZE 533MB ~= x 64MB + 8 XCD x 128KB x 512 steps of h).
//  - h stores: agent-scope write-through (sc0 sc1) -> MALL; release
//    __threadfence removed (syncthreads' vmcnt(0) drain suffices).
//  - h loads: global_load_lds DMA with aux=SC0|SC1 (0x11): coherent at
//    MALL, 32-deep pipelined into per-wave 2x16KB LDS double buffers,
//    XOR-swizzled (kbyte ^= (row&7)<<4) for conflict-free ds_read_b128.
//    Acquire __threadfence removed.
//  - poll relay: wave2 lane0 polls the global epoch; wave3 polls an LDS
//    flag (128 global pollers instead of 256).

#define TT 512
#define BB 64
#define II 1024
#define HHH 1024
#define G4 4096
#define NBLK 128
#define HPB 8

typedef __attribute__((ext_vector_type(8))) short short8;
typedef __attribute__((ext_vector_type(4))) float f32x4;
typedef __attribute__((ext_vector_type(4))) int i32x4;

typedef __attribute__((address_space(1))) const void gvoid;
typedef __attribute__((address_space(3))) void lvoid;

__device__ __forceinline__ short8 load_frag(const unsigned short* p) {
  i32x4 v = *(const i32x4*)p;
  return __builtin_bit_cast(short8, v);
}

__device__ __forceinline__ unsigned short f2bf(float f) {
  unsigned u = __builtin_bit_cast(unsigned, f);
  u = (u + 0x7FFFu + ((u >> 16) & 1u)) >> 16;
  return (unsigned short)u;
}

__device__ __forceinline__ float sigm(float x) {
  return 1.0f / (1.0f + __expf(-x));
}
__device__ __forceinline__ float tanh_f(float x) {
  return 2.0f / (1.0f + __expf(-2.0f * x)) - 1.0f;
}

// ---- conversion kernels ------------------------------------------------
__global__ void cvt_bf16(const float* __restrict__ s,
                         unsigned short* __restrict__ d, int n4) {
  int stride = gridDim.x * blockDim.x;
  for (int i = blockIdx.x * blockDim.x + threadIdx.x; i < n4; i += stride) {
    f32x4 v = *(const f32x4*)(s + 4 * i);
    unsigned lo = (unsigned)f2bf(v[0]) | ((unsigned)f2bf(v[1]) << 16);
    unsigned hi = (unsigned)f2bf(v[2]) | ((unsigned)f2bf(v[3]) << 16);
    uint2 u; u.x = lo; u.y = hi;
    *(uint2*)(d + 4 * i) = u;
  }
}

__global__ void bias_sum(const float* __restrict__ a,
                         const float* __restrict__ b,
                         float* __restrict__ o) {
  int i = blockIdx.x * blockDim.x + threadIdx.x;
  if (i < G4) o[i] = a[i] + b[i];
}

// ---- persistent LSTM kernel -------------------------------------------
// barrier_mem (uint words): [0]=epoch (poll target), [32]=root,
//                           [64 + 32*g]=leaf g (g=0..7). 128B line spacing.
__global__ __launch_bounds__(256, 1) void lstm_persist(
    const unsigned short* __restrict__ xb,    // [T][64][1024] bf16
    const unsigned short* __restrict__ wih,   // [4096][1024] bf16
    const unsigned short* __restrict__ whh,   // [4096][1024] bf16
    const float* __restrict__ bsum,           // [4096] f32 (b_ih + b_hh)
    unsigned short* __restrict__ hbuf,        // 2 x [64][1024] bf16 (zeroed)
    unsigned int* __restrict__ barrier_mem,   // zeroed
    float* __restrict__ out)                  // [64][1024] f32
{
  const int tid = threadIdx.x;
  const int wid = tid >> 6;          // wave 0..3
  const int lane = tid & 63;
  const int ln15 = lane & 15;
  const int quad = lane >> 4;
  const int hc0 = blockIdx.x * HPB;  // this block's first h-column
  const int koff = (wid & 1) * 512;  // K-slice within the wave's matrix
  const bool isx = (wid < 2);        // waves 0,1: x part; waves 2,3: h part
  const unsigned short* wsrc = isx ? wih : whh;

  unsigned int* epoch = barrier_mem;
  unsigned int* root = barrier_mem + 32;
  unsigned int* leaf = barrier_mem + 64 + (blockIdx.x >> 4) * 32;

  __shared__ float red[4][64][36];   // stride 36: quad offsets {0,16,0,16}
                                     // -> 2-way-only write aliasing (free)
  __shared__ __align__(16) short hstage[2][2][8192]; // [h-wave][buf][16KB]
  __shared__ unsigned ready;         // LDS epoch relay (wave2 -> wave3)

  // ---- load persistent B fragments (weights) --------------------------
  // B[k][n] = W[gate_row(n)][k];  n = q*8 + r -> gate_row = q*1024 + hc0 + r
  short8 bfrag[16][2];
#pragma unroll
  for (int nt = 0; nt < 2; ++nt) {
    int n = nt * 16 + ln15;
    int grow = (n >> 3) * 1024 + hc0 + (n & 7);
#pragma unroll
    for (int kc = 0; kc < 16; ++kc) {
      int k = koff + kc * 32 + quad * 8;
      bfrag[kc][nt] = load_frag(wsrc + grow * 1024 + k);
    }
  }

  // ---- elementwise-phase constants ------------------------------------
  const int eb = tid >> 2;   // batch row handled in elementwise phase
  const int erp = tid & 3;   // r-pair: handles r = 2*erp, 2*erp+1
  float bsv[4][2];
#pragma unroll
  for (int q = 0; q < 4; ++q)
#pragma unroll
    for (int rr = 0; rr < 2; ++rr)
      bsv[q][rr] = bsum[q * 1024 + hc0 + erp * 2 + rr];

  // ---- h-staging per-lane constants (h-waves) -------------------------
  // DMA issue j (j=0..15) stages rows j*4+rs, lane-bytes c16, with the
  // XOR swizzle (row&7)<<4 folded into the per-lane GLOBAL address so the
  // LDS stays linear (guide m173 pattern).
  const int wv = wid & 1;                              // h-wave 0/1
  const int rs = lane >> 4;                            // 0..3
  const unsigned c16 = (unsigned)(lane & 15) * 16u;    // byte col in chunk
  const unsigned swe = c16 ^ ((unsigned)rs * 16u);     // j even swizzle
  const unsigned swo = c16 ^ (64u + (unsigned)rs * 16u); // j odd swizzle
  const unsigned slane = (unsigned)rs * 2048u + (unsigned)wv * 1024u;
  // ds_read-side constants
  const unsigned l256 = (unsigned)ln15 * 256u;
  const unsigned lsw = (unsigned)(ln15 & 7) << 4;
  const unsigned q16 = (unsigned)quad * 16u;

  if (tid == 0) ready = 0u;
  __syncthreads();

  float cst[2] = {0.0f, 0.0f};  // c-state, fp32, lives in registers

#pragma unroll 1
  for (int t = 0; t < TT; ++t) {
    const unsigned short* hsrc = hbuf + (t & 1) * (BB * HHH);
    unsigned short* hdst = hbuf + ((t + 1) & 1) * (BB * HHH);

    f32x4 acc[4][2];
#pragma unroll
    for (int m = 0; m < 4; ++m)
#pragma unroll
      for (int nt = 0; nt < 2; ++nt)
        acc[m][nt] = (f32x4){0.0f, 0.0f, 0.0f, 0.0f};

    if (isx) {
      // ---- phase A (x-waves): registers only, cached loads ------------
      const unsigned short* asrc = xb + (size_t)t * (BB * II);
#pragma unroll
      for (int kc = 0; kc < 16; ++kc) {
        int k = koff + kc * 32 + quad * 8;
#pragma unroll
        for (int m = 0; m < 4; ++m) {
          short8 a = load_frag(asrc + (m * 16 + ln15) * 1024 + k);
          acc[m][0] = __builtin_amdgcn_mfma_f32_16x16x32_bf16(
              a, bfrag[kc][0], acc[m][0], 0, 0, 0);
          acc[m][1] = __builtin_amdgcn_mfma_f32_16x16x32_bf16(
              a, bfrag[kc][1], acc[m][1], 0, 0, 0);
        }
      }
    } else {
      // ---- phase A (h-waves): poll epoch, DMA-stage h, MFMA -----------
      if (t) {
        if (wid == 2) {
          if (lane == 0) {
            while (__hip_atomic_load(epoch, __ATOMIC_RELAXED,
                                     __HIP_MEMORY_SCOPE_AGENT) < (unsigned)t)
              __builtin_amdgcn_s_sleep(1);
            __hip_atomic_store(&ready, (unsigned)t, __ATOMIC_RELAXED,
                               __HIP_MEMORY_SCOPE_WORKGROUP);
          }
        } else {
          while (__hip_atomic_load(&ready, __ATOMIC_RELAXED,
                                   __HIP_MEMORY_SCOPE_WORKGROUP) < (unsigned)t)
            __builtin_amdgcn_s_sleep(1);
        }
      }

      const char* gsrc = (const char*)hsrc;

      // stage chunk ck (K-width 128, all 64 rows, 16KB) into buf
      auto stage = [&](int ck, int buf) {
        short* lb = &hstage[wv][buf][0];
#pragma unroll
        for (int j = 0; j < 16; ++j) {
          unsigned off = slane + (unsigned)j * 8192u + (unsigned)ck * 256u +
                         ((j & 1) ? swo : swe);
          __builtin_amdgcn_global_load_lds((gvoid*)(gsrc + off),
                                           (lvoid*)(lb + j * 512),
                                           16, 0, 0x11);  // SC0|SC1
        }
      };
      // consume chunk ck from buf: 16 ds_read_b128 + 32 MFMA
      auto comp = [&](int ck, int buf) {
        const char* lb = (const char*)&hstage[wv][buf][0];
#pragma unroll
        for (int kcl = 0; kcl < 4; ++kcl) {
          int kc = ck * 4 + kcl;
#pragma unroll
          for (int m = 0; m < 4; ++m) {
            unsigned loff = (unsigned)m * 4096u + l256 +
                            (((unsigned)kcl * 64u + q16) ^ lsw);
            short8 a = *(const short8*)(lb + loff);
            acc[m][0] = __builtin_amdgcn_mfma_f32_16x16x32_bf16(
                a, bfrag[kc][0], acc[m][0], 0, 0, 0);
            acc[m][1] = __builtin_amdgcn_mfma_f32_16x16x32_bf16(
                a, bfrag[kc][1], acc[m][1], 0, 0, 0);
          }
        }
      };

      stage(0, 0);
      stage(1, 1);
      asm volatile("s_waitcnt vmcnt(16)" ::: "memory");  // c0 landed
      comp(0, 0);
      asm volatile("s_waitcnt lgkmcnt(0)" ::: "memory"); // b0 reads done
      stage(2, 0);
      asm volatile("s_waitcnt vmcnt(16)" ::: "memory");  // c1 landed
      comp(1, 1);
      asm volatile("s_waitcnt lgkmcnt(0)" ::: "memory"); // b1 reads done
      stage(3, 1);
      asm volatile("s_waitcnt vmcnt(16)" ::: "memory");  // c2 landed
      comp(2, 0);
      asm volatile("s_waitcnt vmcnt(0)" ::: "memory");   // c3 landed
      comp(3, 1);
    }

    // ---- dump partials to LDS (D layout: row=(quad*4+p), col=ln15) ----
#pragma unroll
    for (int m = 0; m < 4; ++m)
#pragma unroll
      for (int nt = 0; nt < 2; ++nt)
#pragma unroll
        for (int p = 0; p < 4; ++p)
          red[wid][m * 16 + quad * 4 + p][nt * 16 + ln15] = acc[m][nt][p];

    __syncthreads();   // (#1)

    // ---- reduce 4 waves + bias, gate nonlinearities, state update -----
    float hv[2];
#pragma unroll
    for (int rr = 0; rr < 2; ++rr) {
      int r = erp * 2 + rr;
      float g[4];
#pragma unroll
      for (int q = 0; q < 4; ++q) {
        int col = q * 8 + r;
        g[q] = red[0][eb][col] + red[1][eb][col] + red[2][eb][col] +
               red[3][eb][col] + bsv[q][rr];
      }
      float ig = sigm(g[0]);
      float fg = sigm(g[1]);
      float gg = tanh_f(g[2]);
      float og = sigm(g[3]);
      float c = fg * cst[rr] + ig * gg;
      cst[rr] = c;
      hv[rr] = og * tanh_f(c);
    }
    unsigned hpack = (unsigned)f2bf(hv[0]) | ((unsigned)f2bf(hv[1]) << 16);
    // agent-scope write-through (sc0 sc1): lands at MALL, so no wbl2
    // release fence is needed — syncthreads' vmcnt(0) drain suffices.
    __hip_atomic_store((unsigned*)(hdst + eb * HHH + hc0 + erp * 2), hpack,
                       __ATOMIC_RELAXED, __HIP_MEMORY_SCOPE_AGENT);

    if (t == TT - 1) {
      float2 o2; o2.x = hv[0]; o2.y = hv[1];
      *(float2*)(out + eb * HHH + hc0 + erp * 2) = o2;
    }

    __syncthreads();   // (#2) all h stores vmcnt-drained by every thread

    // ---- arrival: 2-level tree, single-writer epoch broadcast ---------
    if (t < TT - 1 && tid == 0) {
      unsigned old = atomicAdd(leaf, 1u);
      if (old == (unsigned)t * 16u + 15u) {        // last of 16 in group
        unsigned old2 = atomicAdd(root, 1u);
        if (old2 == (unsigned)t * 8u + 7u)         // last of 8 groups
          atomicExch(epoch, (unsigned)(t + 1));    // RMW: agent-visible
      }
    }
    // x-waves fall through to step t+1 immediately; h-waves poll there.
  }
}

// ---- launcher ----------------------------------------------------------
extern "C" void kernel_launch(void* const* d_in, const int* in_sizes, int n_in,
                              void* d_out, int out_size, void* d_ws,
                              size_t ws_size, hipStream_t stream) {
  (void)in_sizes; (void)n_in; (void)out_size; (void)ws_size;
  const float* x   = (const float*)d_in[0];
  const float* wih = (const float*)d_in[1];
  const float* whh = (const float*)d_in[2];
  const float* bih = (const float*)d_in[3];
  const float* bhh = (const float*)d_in[4];

  char* ws = (char*)d_ws;
  // workspace layout (bytes):
  //   [0, 4096)          barrier: epoch/root/leaf counters (128B-spaced)
  //   [4096, +256KiB)    h double buffer (2 x 64x1024 bf16)
  //   [1MiB, 9MiB)       W_ih bf16
  //   [9MiB, 17MiB)      W_hh bf16
  //   [17MiB, +16KiB)    bias sum f32
  //   [18MiB, 82MiB)     x bf16
  unsigned int*   bar  = (unsigned int*)(ws);
  unsigned short* hb   = (unsigned short*)(ws + 4096);
  unsigned short* wihb = (unsigned short*)(ws + (1ull << 20));
  unsigned short* whhb = (unsigned short*)(ws + (9ull << 20));
  float*          bs   = (float*)(ws + (17ull << 20));
  unsigned short* xb   = (unsigned short*)(ws + (18ull << 20));

  // zero barrier + h buffers (ws is poisoned 0xAA before every launch)
  hipMemsetAsync(ws, 0, 4096 + 2ull * BB * HHH * sizeof(unsigned short),
                 stream);

  cvt_bf16<<<2048, 256, 0, stream>>>(x, xb, (TT * BB * II) / 4);
  cvt_bf16<<<1024, 256, 0, stream>>>(wih, wihb, (G4 * II) / 4);
  cvt_bf16<<<1024, 256, 0, stream>>>(whh, whhb, (G4 * HHH) / 4);
  bias_sum<<<16, 256, 0, stream>>>(bih, bhh, bs);

  lstm_persist<<<NBLK, 256, 0, stream>>>(xb, wihb, whhb, bs, hb, bar,
                                         (float*)d_out);
}

// Round 2
// 3435.677 us; speedup vs baseline: 2.5239x; 1.4624x over previous
//
#include <hip/hip_runtime.h>

// LSTM_3813930958978: T=512, B=64, I=1024, H=1024, gate order i,f,g,o.
// Persistent cooperative kernel, 128 blocks x 256 threads (1 block/CU).
// Block k owns h-columns [8k, 8k+8) => 32 gate columns.
// Weights live in registers as MFMA B-fragments (K split over 2 waves per
// matrix). Waves 0,1 compute x_t @ W_ih^T (never wait on the global
// barrier); waves 2,3 poll the epoch word, then compute h @ W_hh^T.
//
// R1: h-path via global_load_lds DMA (SC0|SC1, MALL-coherent), fences
//     removed, poll relay. 8490 -> 4845 us.
// R2 (this round): x-path gets the same DMA treatment. bfrag pins 128
//     VGPRs, so the old register A-loads had ~no pipelining headroom
//     (~64 serialized-ish L2-miss loads/step = the dominant ~6 us).
//     x_t now staged via global_load_lds (aux=0: L2-cacheable, read-only)
//     into 3 rotating 8KB LDS chunks per x-wave, XOR-swizzled through the
//     per-lane GLOBAL address (LDS dest stays linear, m173 pattern) so
//     ds_read_b128 fragment reads are conflict-free.

#define TT 512
#define BB 64
#define II 1024
#define HHH 1024
#define G4 4096
#define NBLK 128
#define HPB 8

typedef __attribute__((ext_vector_type(8))) short short8;
typedef __attribute__((ext_vector_type(4))) float f32x4;
typedef __attribute__((ext_vector_type(4))) int i32x4;

typedef __attribute__((address_space(1))) const void gvoid;
typedef __attribute__((address_space(3))) void lvoid;

__device__ __forceinline__ short8 load_frag(const unsigned short* p) {
  i32x4 v = *(const i32x4*)p;
  return __builtin_bit_cast(short8, v);
}

__device__ __forceinline__ unsigned short f2bf(float f) {
  unsigned u = __builtin_bit_cast(unsigned, f);
  u = (u + 0x7FFFu + ((u >> 16) & 1u)) >> 16;
  return (unsigned short)u;
}

__device__ __forceinline__ float sigm(float x) {
  return 1.0f / (1.0f + __expf(-x));
}
__device__ __forceinline__ float tanh_f(float x) {
  return 2.0f / (1.0f + __expf(-2.0f * x)) - 1.0f;
}

// ---- conversion kernels ------------------------------------------------
__global__ void cvt_bf16(const float* __restrict__ s,
                         unsigned short* __restrict__ d, int n4) {
  int stride = gridDim.x * blockDim.x;
  for (int i = blockIdx.x * blockDim.x + threadIdx.x; i < n4; i += stride) {
    f32x4 v = *(const f32x4*)(s + 4 * i);
    unsigned lo = (unsigned)f2bf(v[0]) | ((unsigned)f2bf(v[1]) << 16);
    unsigned hi = (unsigned)f2bf(v[2]) | ((unsigned)f2bf(v[3]) << 16);
    uint2 u; u.x = lo; u.y = hi;
    *(uint2*)(d + 4 * i) = u;
  }
}

__global__ void bias_sum(const float* __restrict__ a,
                         const float* __restrict__ b,
                         float* __restrict__ o) {
  int i = blockIdx.x * blockDim.x + threadIdx.x;
  if (i < G4) o[i] = a[i] + b[i];
}

// ---- persistent LSTM kernel -------------------------------------------
// barrier_mem (uint words): [0]=epoch (poll target), [32]=root,
//                           [64 + 32*g]=leaf g (g=0..7). 128B line spacing.
__global__ __launch_bounds__(256, 1) void lstm_persist(
    const unsigned short* __restrict__ xb,    // [T][64][1024] bf16
    const unsigned short* __restrict__ wih,   // [4096][1024] bf16
    const unsigned short* __restrict__ whh,   // [4096][1024] bf16
    const float* __restrict__ bsum,           // [4096] f32 (b_ih + b_hh)
    unsigned short* __restrict__ hbuf,        // 2 x [64][1024] bf16 (zeroed)
    unsigned int* __restrict__ barrier_mem,   // zeroed
    float* __restrict__ out)                  // [64][1024] f32
{
  const int tid = threadIdx.x;
  const int wid = tid >> 6;          // wave 0..3
  const int lane = tid & 63;
  const int ln15 = lane & 15;
  const int quad = lane >> 4;
  const int hc0 = blockIdx.x * HPB;  // this block's first h-column
  const int koff = (wid & 1) * 512;  // K-slice within the wave's matrix
  const bool isx = (wid < 2);        // waves 0,1: x part; waves 2,3: h part
  const unsigned short* wsrc = isx ? wih : whh;

  unsigned int* epoch = barrier_mem;
  unsigned int* root = barrier_mem + 32;
  unsigned int* leaf = barrier_mem + 64 + (blockIdx.x >> 4) * 32;

  __shared__ float red[4][64][36];   // stride 36: quad offsets {0,16,0,16}
  __shared__ __align__(16) short hstage[2][2][8192]; // [h-wave][buf][16KB]
  __shared__ __align__(16) short xstage[2][3][4096]; // [x-wave][buf][8KB]
  __shared__ unsigned ready;         // LDS epoch relay (wave2 -> wave3)

  // ---- load persistent B fragments (weights) --------------------------
  // B[k][n] = W[gate_row(n)][k];  n = q*8 + r -> gate_row = q*1024 + hc0 + r
  short8 bfrag[16][2];
#pragma unroll
  for (int nt = 0; nt < 2; ++nt) {
    int n = nt * 16 + ln15;
    int grow = (n >> 3) * 1024 + hc0 + (n & 7);
#pragma unroll
    for (int kc = 0; kc < 16; ++kc) {
      int k = koff + kc * 32 + quad * 8;
      bfrag[kc][nt] = load_frag(wsrc + grow * 1024 + k);
    }
  }

  // ---- elementwise-phase constants ------------------------------------
  const int eb = tid >> 2;   // batch row handled in elementwise phase
  const int erp = tid & 3;   // r-pair: handles r = 2*erp, 2*erp+1
  float bsv[4][2];
#pragma unroll
  for (int q = 0; q < 4; ++q)
#pragma unroll
    for (int rr = 0; rr < 2; ++rr)
      bsv[q][rr] = bsum[q * 1024 + hc0 + erp * 2 + rr];

  // ---- h-staging per-lane constants (h-waves) -------------------------
  // DMA issue j (j=0..15) stages rows j*4+rs, lane-bytes c16, with the
  // XOR swizzle (row&7)<<4 folded into the per-lane GLOBAL address so the
  // LDS stays linear (m173 pattern).
  const int wv = wid & 1;                              // h-wave 0/1
  const int rs = lane >> 4;                            // 0..3
  const unsigned c16 = (unsigned)(lane & 15) * 16u;    // byte col in chunk
  const unsigned swe = c16 ^ ((unsigned)rs * 16u);     // j even swizzle
  const unsigned swo = c16 ^ (64u + (unsigned)rs * 16u); // j odd swizzle
  const unsigned slane = (unsigned)rs * 2048u + (unsigned)wv * 1024u;
  // ---- x-staging per-lane constants (x-waves) -------------------------
  // DMA issue j stages rows j*8 + (lane>>3); row's 128B chunk-slice is
  // 16B-swizzled by (row&7) = lane>>3.
  const unsigned xrow = (unsigned)(lane >> 3);         // 0..7
  const unsigned xlane = xrow * 2048u + (unsigned)wid * 1024u +
                         (((unsigned)(lane & 7) ^ xrow) * 16u);
  // ---- ds_read-side constants -----------------------------------------
  const unsigned l256 = (unsigned)ln15 * 256u;  // h row-slot stride
  const unsigned l128 = (unsigned)ln15 * 128u;  // x row-slot stride
  const unsigned lsw = (unsigned)(ln15 & 7) << 4;
  const unsigned q16 = (unsigned)quad * 16u;

  if (tid == 0) ready = 0u;
  __syncthreads();

  float cst[2] = {0.0f, 0.0f};  // c-state, fp32, lives in registers

#pragma unroll 1
  for (int t = 0; t < TT; ++t) {
    const unsigned short* hsrc = hbuf + (t & 1) * (BB * HHH);
    unsigned short* hdst = hbuf + ((t + 1) & 1) * (BB * HHH);

    f32x4 acc[4][2];
#pragma unroll
    for (int m = 0; m < 4; ++m)
#pragma unroll
      for (int nt = 0; nt < 2; ++nt)
        acc[m][nt] = (f32x4){0.0f, 0.0f, 0.0f, 0.0f};

    if (isx) {
      // ---- phase A (x-waves): DMA-stage x_t, MFMA ---------------------
      const char* gxs = (const char*)xb + (size_t)t * 131072u;

      // stage chunk ck (K-width 64 elems, 64 rows, 8KB) into buf
      auto stage_x = [&](int ck, int buf) {
        short* lb = &xstage[wid][buf][0];
#pragma unroll
        for (int j = 0; j < 8; ++j) {
          unsigned off = xlane + (unsigned)j * 16384u + (unsigned)ck * 128u;
          __builtin_amdgcn_global_load_lds((gvoid*)(gxs + off),
                                           (lvoid*)(lb + j * 512),
                                           16, 0, 0);  // cached, L2-shared
        }
      };
      // consume chunk ck from buf: 8 ds_read_b128 + 16 MFMA
      auto comp_x = [&](int ck, int buf) {
        const char* lb = (const char*)&xstage[wid][buf][0];
#pragma unroll
        for (int kl = 0; kl < 2; ++kl) {
          int kc = ck * 2 + kl;
#pragma unroll
          for (int m = 0; m < 4; ++m) {
            unsigned loff = (unsigned)m * 2048u + l128 +
                            (((unsigned)kl * 64u + q16) ^ lsw);
            short8 a = *(const short8*)(lb + loff);
            acc[m][0] = __builtin_amdgcn_mfma_f32_16x16x32_bf16(
                a, bfrag[kc][0], acc[m][0], 0, 0, 0);
            acc[m][1] = __builtin_amdgcn_mfma_f32_16x16x32_bf16(
                a, bfrag[kc][1], acc[m][1], 0, 0, 0);
          }
        }
      };

      stage_x(0, 0); stage_x(1, 1); stage_x(2, 2);
      asm volatile("s_waitcnt vmcnt(16)" ::: "memory");
      comp_x(0, 0);
      asm volatile("s_waitcnt lgkmcnt(0)" ::: "memory");
      stage_x(3, 0);
      asm volatile("s_waitcnt vmcnt(16)" ::: "memory");
      comp_x(1, 1);
      asm volatile("s_waitcnt lgkmcnt(0)" ::: "memory");
      stage_x(4, 1);
      asm volatile("s_waitcnt vmcnt(16)" ::: "memory");
      comp_x(2, 2);
      asm volatile("s_waitcnt lgkmcnt(0)" ::: "memory");
      stage_x(5, 2);
      asm volatile("s_waitcnt vmcnt(16)" ::: "memory");
      comp_x(3, 0);
      asm volatile("s_waitcnt lgkmcnt(0)" ::: "memory");
      stage_x(6, 0);
      asm volatile("s_waitcnt vmcnt(16)" ::: "memory");
      comp_x(4, 1);
      asm volatile("s_waitcnt lgkmcnt(0)" ::: "memory");
      stage_x(7, 1);
      asm volatile("s_waitcnt vmcnt(16)" ::: "memory");
      comp_x(5, 2);
      asm volatile("s_waitcnt vmcnt(8)" ::: "memory");
      comp_x(6, 0);
      asm volatile("s_waitcnt vmcnt(0)" ::: "memory");
      comp_x(7, 1);
    } else {
      // ---- phase A (h-waves): poll epoch, DMA-stage h, MFMA -----------
      if (t) {
        if (wid == 2) {
          if (lane == 0) {
            while (__hip_atomic_load(epoch, __ATOMIC_RELAXED,
                                     __HIP_MEMORY_SCOPE_AGENT) < (unsigned)t)
              __builtin_amdgcn_s_sleep(1);
            __hip_atomic_store(&ready, (unsigned)t, __ATOMIC_RELAXED,
                               __HIP_MEMORY_SCOPE_WORKGROUP);
          }
        } else {
          while (__hip_atomic_load(&ready, __ATOMIC_RELAXED,
                                   __HIP_MEMORY_SCOPE_WORKGROUP) < (unsigned)t)
            __builtin_amdgcn_s_sleep(1);
        }
      }

      const char* gsrc = (const char*)hsrc;

      // stage chunk ck (K-width 128, all 64 rows, 16KB) into buf
      auto stage = [&](int ck, int buf) {
        short* lb = &hstage[wv][buf][0];
#pragma unroll
        for (int j = 0; j < 16; ++j) {
          unsigned off = slane + (unsigned)j * 8192u + (unsigned)ck * 256u +
                         ((j & 1) ? swo : swe);
          __builtin_amdgcn_global_load_lds((gvoid*)(gsrc + off),
                                           (lvoid*)(lb + j * 512),
                                           16, 0, 0x11);  // SC0|SC1
        }
      };
      // consume chunk ck from buf: 16 ds_read_b128 + 32 MFMA
      auto comp = [&](int ck, int buf) {
        const char* lb = (const char*)&hstage[wv][buf][0];
#pragma unroll
        for (int kcl = 0; kcl < 4; ++kcl) {
          int kc = ck * 4 + kcl;
#pragma unroll
          for (int m = 0; m < 4; ++m) {
            unsigned loff = (unsigned)m * 4096u + l256 +
                            (((unsigned)kcl * 64u + q16) ^ lsw);
            short8 a = *(const short8*)(lb + loff);
            acc[m][0] = __builtin_amdgcn_mfma_f32_16x16x32_bf16(
                a, bfrag[kc][0], acc[m][0], 0, 0, 0);
            acc[m][1] = __builtin_amdgcn_mfma_f32_16x16x32_bf16(
                a, bfrag[kc][1], acc[m][1], 0, 0, 0);
          }
        }
      };

      stage(0, 0);
      stage(1, 1);
      asm volatile("s_waitcnt vmcnt(16)" ::: "memory");  // c0 landed
      comp(0, 0);
      asm volatile("s_waitcnt lgkmcnt(0)" ::: "memory"); // b0 reads done
      stage(2, 0);
      asm volatile("s_waitcnt vmcnt(16)" ::: "memory");  // c1 landed
      comp(1, 1);
      asm volatile("s_waitcnt lgkmcnt(0)" ::: "memory"); // b1 reads done
      stage(3, 1);
      asm volatile("s_waitcnt vmcnt(16)" ::: "memory");  // c2 landed
      comp(2, 0);
      asm volatile("s_waitcnt vmcnt(0)" ::: "memory");   // c3 landed
      comp(3, 1);
    }

    // ---- dump partials to LDS (D layout: row=(quad*4+p), col=ln15) ----
#pragma unroll
    for (int m = 0; m < 4; ++m)
#pragma unroll
      for (int nt = 0; nt < 2; ++nt)
#pragma unroll
        for (int p = 0; p < 4; ++p)
          red[wid][m * 16 + quad * 4 + p][nt * 16 + ln15] = acc[m][nt][p];

    __syncthreads();   // (#1)

    // ---- reduce 4 waves + bias, gate nonlinearities, state update -----
    float hv[2];
#pragma unroll
    for (int rr = 0; rr < 2; ++rr) {
      int r = erp * 2 + rr;
      float g[4];
#pragma unroll
      for (int q = 0; q < 4; ++q) {
        int col = q * 8 + r;
        g[q] = red[0][eb][col] + red[1][eb][col] + red[2][eb][col] +
               red[3][eb][col] + bsv[q][rr];
      }
      float ig = sigm(g[0]);
      float fg = sigm(g[1]);
      float gg = tanh_f(g[2]);
      float og = sigm(g[3]);
      float c = fg * cst[rr] + ig * gg;
      cst[rr] = c;
      hv[rr] = og * tanh_f(c);
    }
    unsigned hpack = (unsigned)f2bf(hv[0]) | ((unsigned)f2bf(hv[1]) << 16);
    // agent-scope write-through (sc0 sc1): lands at MALL; syncthreads'
    // vmcnt(0) drain makes it visible before the arrival tree fires.
    __hip_atomic_store((unsigned*)(hdst + eb * HHH + hc0 + erp * 2), hpack,
                       __ATOMIC_RELAXED, __HIP_MEMORY_SCOPE_AGENT);

    if (t == TT - 1) {
      float2 o2; o2.x = hv[0]; o2.y = hv[1];
      *(float2*)(out + eb * HHH + hc0 + erp * 2) = o2;
    }

    __syncthreads();   // (#2) all h stores vmcnt-drained by every thread

    // ---- arrival: 2-level tree, single-writer epoch broadcast ---------
    if (t < TT - 1 && tid == 0) {
      unsigned old = atomicAdd(leaf, 1u);
      if (old == (unsigned)t * 16u + 15u) {        // last of 16 in group
        unsigned old2 = atomicAdd(root, 1u);
        if (old2 == (unsigned)t * 8u + 7u)         // last of 8 groups
          atomicExch(epoch, (unsigned)(t + 1));    // RMW: agent-visible
      }
    }
    // x-waves fall through to step t+1 immediately; h-waves poll there.
  }
}

// ---- launcher ----------------------------------------------------------
extern "C" void kernel_launch(void* const* d_in, const int* in_sizes, int n_in,
                              void* d_out, int out_size, void* d_ws,
                              size_t ws_size, hipStream_t stream) {
  (void)in_sizes; (void)n_in; (void)out_size; (void)ws_size;
  const float* x   = (const float*)d_in[0];
  const float* wih = (const float*)d_in[1];
  const float* whh = (const float*)d_in[2];
  const float* bih = (const float*)d_in[3];
  const float* bhh = (const float*)d_in[4];

  char* ws = (char*)d_ws;
  // workspace layout (bytes):
  //   [0, 4096)          barrier: epoch/root/leaf counters (128B-spaced)
  //   [4096, +256KiB)    h double buffer (2 x 64x1024 bf16)
  //   [1MiB, 9MiB)       W_ih bf16
  //   [9MiB, 17MiB)      W_hh bf16
  //   [17MiB, +16KiB)    bias sum f32
  //   [18MiB, 82MiB)     x bf16
  unsigned int*   bar  = (unsigned int*)(ws);
  unsigned short* hb   = (unsigned short*)(ws + 4096);
  unsigned short* wihb = (unsigned short*)(ws + (1ull << 20));
  unsigned short* whhb = (unsigned short*)(ws + (9ull << 20));
  float*          bs   = (float*)(ws + (17ull << 20));
  unsigned short* xb   = (unsigned short*)(ws + (18ull << 20));

  // zero barrier + h buffers (ws is poisoned 0xAA before every launch)
  hipMemsetAsync(ws, 0, 4096 + 2ull * BB * HHH * sizeof(unsigned short),
                 stream);

  cvt_bf16<<<2048, 256, 0, stream>>>(x, xb, (TT * BB * II) / 4);
  cvt_bf16<<<1024, 256, 0, stream>>>(wih, wihb, (G4 * II) / 4);
  cvt_bf16<<<1024, 256, 0, stream>>>(whh, whhb, (G4 * HHH) / 4);
  bias_sum<<<16, 256, 0, stream>>>(bih, bhh, bs);

  lstm_persist<<<NBLK, 256, 0, stream>>>(xb, wihb, whhb, bs, hb, bar,
                                         (float*)d_out);
}